// Round 7
// baseline (309.182 us; speedup 1.0000x reference)
//
#include <hip/hip_runtime.h>
#include <stdint.h>

#define NB 4096          // coarse buckets (top 12 bits of monotone key)
#define BSH 20
#define RSH 14           // refined buckets: 64x finer
#define HS 512
#define HM 511
#define CAP 8192         // candidate capacity
#define PCAP 4096        // pruned-candidate capacity
#define NRB 2048         // refined buckets
#define NT 1024
#define NW 16            // waves per block
#define NTS 256          // store-role threads (4 waves)
#define NTC 768          // compute-role threads (12 waves)

typedef unsigned long long ull;
typedef float vf4 __attribute__((ext_vector_type(4)));

// ---- monotonic float<->uint mapping: larger float => larger uint ----
__device__ __forceinline__ unsigned mono_u32(float x) {
    unsigned b = __float_as_uint(x);
    return (b & 0x80000000u) ? ~b : (b | 0x80000000u);
}
__device__ __forceinline__ float inv_mono(unsigned u) {
    unsigned b = (u & 0x80000000u) ? (u & 0x7fffffffu) : ~u;
    return __uint_as_float(b);
}

// numpy op order: pen = freq*cnt + pres*(cnt>0); x = (l - pen) / t
__device__ __forceinline__ float compute_x(float l, int cnt,
                                           float pres, float freq, float t) {
    float pen = __fadd_rn(__fmul_rn(freq, (float)cnt), (cnt > 0) ? pres : 0.0f);
    return __fdiv_rn(__fsub_rn(l, pen), t);
}

__device__ __forceinline__ int hash_lookup(const int* hkey, const int* hval, int v) {
    unsigned h = ((unsigned)v * 2654435761u) >> 23;
    while (true) {
        int kk = hkey[h];
        if (kk == v) return hval[h];
        if (kk == -1) return 0;
        h = (h + 1) & HM;
    }
}

// block-wide: sum of acc over all threads with tid' > tid (2 barriers)
__device__ __forceinline__ int wave_suffix_above(int acc, int tid, int* wq) {
    int lane = tid & 63, wv = tid >> 6;
    int v = acc;
#pragma unroll
    for (int off = 1; off < 64; off <<= 1) {
        int x = __shfl_down(v, off);
        if (lane + off < 64) v += x;
    }
    if (lane == 0) wq[wv] = v;      // wave suffix-total (lane0 holds full wave sum)
    __syncthreads();
    int ws = 0;
    for (int w = wv + 1; w < NW; ++w) ws += wq[w];
    return (v - acc) + ws;
}

// max bucket b (4/thread) with block-wide suffix count >= k
__device__ int suffix_cut4(const unsigned* hc, int* wq, int* sh, int k, int tid) {
    if (tid == 0) *sh = -1;
    int base = tid * 4;
    int c0 = hc[base], c1 = hc[base + 1], c2 = hc[base + 2], c3 = hc[base + 3];
    int s3 = c3, s2 = s3 + c2, s1 = s2 + c1, s0 = s1 + c0;
    int above = wave_suffix_above(s0, tid, wq);
    int best = -1;
    if (s3 + above >= k) best = base + 3;
    else if (s2 + above >= k) best = base + 2;
    else if (s1 + above >= k) best = base + 1;
    else if (s0 + above >= k) best = base + 0;
    if (best >= 0) atomicMax(sh, best);
    __syncthreads();
    int r = *sh;
    __syncthreads();
    return r;
}

__global__ __launch_bounds__(NT) void k_fused(
    const float* __restrict__ logits, const int* __restrict__ tokens,
    const float* __restrict__ pres_v, const float* __restrict__ freq_v,
    const float* __restrict__ temps, const float* __restrict__ topp_v,
    const int* __restrict__ topk_v, int V, int H, float* __restrict__ out)
{
    __shared__ ull skey[CAP];                 // 64 KB: candidates
    __shared__ ull hreg[4096];                // 32 KB: hc / rh / tmpc / se
    __shared__ int hkey[HS], hval[HS];        // 4 KB: penalty hash
    __shared__ int wqi[NW];
    __shared__ float wqf[NW];
    __shared__ float esum_s, corr_s;
    __shared__ int cut_s, lcnt_s, rb_s, pcnt_s;

    unsigned* hc = (unsigned*)hreg;           // 4096 u32
    float* se = (float*)hreg;                 // 8192 f32 (after hc dead)

    int row = blockIdx.x, tid = threadIdx.x;
    for (int b = tid; b < NB; b += NT) hc[b] = 0u;
    for (int i = tid; i < HS; i += NT) { hkey[i] = -1; hval[i] = 0; }
    if (tid == 0) { esum_s = 0.f; corr_s = 0.f; lcnt_s = 0; rb_s = 0; pcnt_s = 0; }
    __syncthreads();

    // ---- build penalty-token hash ----
    const int* trow = tokens + (size_t)row * H;
    for (int i = tid; i < H; i += NT) {
        int v = trow[i];
        unsigned h = ((unsigned)v * 2654435761u) >> 23;
        while (true) {
            int prev = atomicCAS(&hkey[h], -1, v);
            if (prev == -1 || prev == v) { atomicAdd(&hval[h], 1); break; }
            h = (h + 1) & HM;
        }
    }

    float t = temps[row];
    float r = __fdiv_rn(1.0f, t);     // same approx everywhere
    float pres = pres_v[row], freq = freq_v[row];
    int active = (pres >= 1e-5f) || (freq >= 1e-5f);
    int k = topk_v[row];
    const float* lrow = logits + (size_t)row * V;
    const vf4* l4p = (const vf4*)lrow;
    int V4 = V >> 2;
    __syncthreads();

    // ---- Phase S: sampled histogram (~1/16, compute waves only) ----
    int S4 = V4 >> 4;
    if (tid >= NTS) {
        for (int j = tid - NTS; j < S4; j += NTC) {
            int c = j >> 6;
            int g = (((c << 4) + (c & 15)) << 6) | (j & 63);
            if (g < V4) {
                vf4 A = l4p[g];
#pragma unroll
                for (int jj = 0; jj < 4; ++jj)
                    atomicAdd(&hc[mono_u32(__fmul_rn(A[jj], r)) >> BSH], 1u);
            }
        }
    }
    __syncthreads();
    float ms = (S4 > 0) ? ((float)k * (float)(S4 << 2) / (float)V) : 0.0f;
    int req = (int)(ms + 8.0f * sqrtf(ms) + 16.0f);
    int bT = (S4 > 0) ? suffix_cut4(hc, wqi, &cut_s, req, tid) : 0;
    int thr = bT - 1; if (thr < 0) thr = 0;
    for (int b = tid; b < NB; b += NT) hc[b] = 0u;
    __syncthreads();

    // ---- Phase A: wave-specialized streaming ----
    // waves 0..3: pure nontemporal zero-store stream (fire-and-forget)
    // waves 4..15: pure nontemporal load stream + Sexp + sparse hist + compact
    vf4* o4p = (vf4*)(out + (size_t)row * V);
    if (tid < NTS) {
        vf4 z4 = {0.f, 0.f, 0.f, 0.f};
        int i = tid;
        for (; i + 7 * NTS < V4; i += 8 * NTS) {
#pragma unroll
            for (int q = 0; q < 8; ++q)
                __builtin_nontemporal_store(z4, &o4p[i + q * NTS]);
        }
        for (; i < V4; i += NTS) __builtin_nontemporal_store(z4, &o4p[i]);
        for (int v = (V4 << 2) + tid; v < V; v += NTS) out[(size_t)row * V + v] = 0.0f;
    } else {
        int ctid = tid - NTS;
        float es0 = 0.f, es1 = 0.f, es2 = 0.f, es3 = 0.f;
        int i = ctid;
        for (; i + 7 * NTC < V4; i += 8 * NTC) {
            vf4 arr[8];
#pragma unroll
            for (int q = 0; q < 8; ++q)
                arr[q] = __builtin_nontemporal_load(&l4p[i + q * NTC]);
#pragma unroll
            for (int q = 0; q < 8; ++q) {
                int vb = (i + q * NTC) << 2;
                float x0 = __fmul_rn(arr[q][0], r), x1 = __fmul_rn(arr[q][1], r);
                float x2 = __fmul_rn(arr[q][2], r), x3 = __fmul_rn(arr[q][3], r);
                es0 += __expf(x0); es1 += __expf(x1); es2 += __expf(x2); es3 += __expf(x3);
                unsigned u0 = mono_u32(x0), u1 = mono_u32(x1);
                unsigned u2 = mono_u32(x2), u3 = mono_u32(x3);
                if ((int)(u0 >> BSH) >= thr) {
                    atomicAdd(&hc[u0 >> BSH], 1u);
                    int pos = atomicAdd(&lcnt_s, 1);
                    if (pos < CAP) skey[pos] = ((ull)u0 << 32) | (unsigned)~(unsigned)(vb);
                }
                if ((int)(u1 >> BSH) >= thr) {
                    atomicAdd(&hc[u1 >> BSH], 1u);
                    int pos = atomicAdd(&lcnt_s, 1);
                    if (pos < CAP) skey[pos] = ((ull)u1 << 32) | (unsigned)~(unsigned)(vb + 1);
                }
                if ((int)(u2 >> BSH) >= thr) {
                    atomicAdd(&hc[u2 >> BSH], 1u);
                    int pos = atomicAdd(&lcnt_s, 1);
                    if (pos < CAP) skey[pos] = ((ull)u2 << 32) | (unsigned)~(unsigned)(vb + 2);
                }
                if ((int)(u3 >> BSH) >= thr) {
                    atomicAdd(&hc[u3 >> BSH], 1u);
                    int pos = atomicAdd(&lcnt_s, 1);
                    if (pos < CAP) skey[pos] = ((ull)u3 << 32) | (unsigned)~(unsigned)(vb + 3);
                }
            }
        }
        for (; i < V4; i += NTC) {
            vf4 A = __builtin_nontemporal_load(&l4p[i]);
#pragma unroll
            for (int j = 0; j < 4; ++j) {
                float x = __fmul_rn(A[j], r);
                es0 += __expf(x);
                unsigned u = mono_u32(x);
                if ((int)(u >> BSH) >= thr) {
                    atomicAdd(&hc[u >> BSH], 1u);
                    int pos = atomicAdd(&lcnt_s, 1);
                    if (pos < CAP) skey[pos] = ((ull)u << 32) | (unsigned)~(unsigned)((i << 2) + j);
                }
            }
        }
        for (int v = (V4 << 2) + ctid; v < V; v += NTC) {
            float x = __fmul_rn(lrow[v], r);
            es0 += __expf(x);
            unsigned u = mono_u32(x);
            if ((int)(u >> BSH) >= thr) {
                atomicAdd(&hc[u >> BSH], 1u);
                int pos = atomicAdd(&lcnt_s, 1);
                if (pos < CAP) skey[pos] = ((ull)u << 32) | (unsigned)~(unsigned)v;
            }
        }
        float es = (es0 + es1) + (es2 + es3);
        for (int off = 32; off; off >>= 1) es += __shfl_down(es, off);
        if ((tid & 63) == 0) atomicAdd(&esum_s, es);
    }
    __syncthreads();

    // ---- penalty corrections: hist moves + Sexp delta ----
    float corr = 0.0f;
    if (active) {
        for (int s = tid; s < HS; s += NT) {
            int v = hkey[s];
            if (v >= 0) {
                int c = hval[s];
                float l = lrow[v];
                float x0 = __fmul_rn(l, r);
                float xp = compute_x(l, c, pres, freq, t);
                int b0 = (int)(mono_u32(x0) >> BSH);
                int bp = (int)(mono_u32(xp) >> BSH);
                if (b0 != bp) {
                    if (b0 >= thr) atomicSub(&hc[b0], 1u);
                    if (bp >= thr) atomicAdd(&hc[bp], 1u);
                }
                corr += __expf(xp) - __expf(x0);
            }
        }
    }
    for (int off = 32; off; off >>= 1) corr += __shfl_down(corr, off);
    if ((tid & 63) == 0) atomicAdd(&corr_s, corr);
    __syncthreads();
    int lraw = lcnt_s;
    int count = lraw > CAP ? CAP : lraw;

    // ---- key fix-up: exact (penalized) keys for candidates ----
    for (int j = tid; j < count; j += NT) {
        unsigned idx = ~(unsigned)(skey[j] & 0xffffffffull);
        float l = lrow[idx];
        int c = active ? hash_lookup(hkey, hval, (int)idx) : 0;
        unsigned ue = (c > 0) ? mono_u32(compute_x(l, c, pres, freq, t))
                              : mono_u32(__fdiv_rn(l, t));
        skey[j] = ((ull)ue << 32) | (unsigned)~idx;
    }
    __syncthreads();

    int bst = suffix_cut4(hc, wqi, &cut_s, k, tid);
    // need 2 buckets of slack: candidates(approx>=thr) must cover exact>=bst-1
    bool ok = (bst >= thr + 2) && (lraw <= CAP);

    if (!ok) {
        // ---- fallback: exact full-histogram path (cold, ~never taken) ----
        for (int b = tid; b < NB; b += NT) hc[b] = 0u;
        if (tid == 0) lcnt_s = 0;
        __syncthreads();
        for (int v = tid; v < V; v += NT)
            atomicAdd(&hc[mono_u32(__fmul_rn(lrow[v], r)) >> BSH], 1u);
        __syncthreads();
        if (active) {
            for (int s = tid; s < HS; s += NT) {
                int v = hkey[s];
                if (v >= 0) {
                    int c = hval[s];
                    float l = lrow[v];
                    int b0 = (int)(mono_u32(__fmul_rn(l, r)) >> BSH);
                    int bp = (int)(mono_u32(compute_x(l, c, pres, freq, t)) >> BSH);
                    if (b0 != bp) { atomicSub(&hc[b0], 1u); atomicAdd(&hc[bp], 1u); }
                }
            }
        }
        __syncthreads();
        bst = suffix_cut4(hc, wqi, &cut_s, k, tid);
        int thr2 = bst - 2; if (thr2 < 0) thr2 = 0;
        for (int v = tid; v < V; v += NT) {
            unsigned u = mono_u32(__fmul_rn(lrow[v], r));
            if ((int)(u >> BSH) >= thr2) {
                int pos = atomicAdd(&lcnt_s, 1);
                if (pos < CAP) skey[pos] = ((ull)u << 32) | (unsigned)~(unsigned)v;
            }
        }
        __syncthreads();
        count = lcnt_s > CAP ? CAP : lcnt_s;
        for (int j = tid; j < count; j += NT) {
            unsigned idx = ~(unsigned)(skey[j] & 0xffffffffull);
            float l = lrow[idx];
            int c = active ? hash_lookup(hkey, hval, (int)idx) : 0;
            unsigned ue = (c > 0) ? mono_u32(compute_x(l, c, pres, freq, t))
                                  : mono_u32(__fdiv_rn(l, t));
            skey[j] = ((ull)ue << 32) | (unsigned)~idx;
        }
        __syncthreads();
    }
    float Sp = esum_s + corr_s;

    // ---- Phase D: refined cut on exact keys + prune (only if sort is big) ----
    if (count > 2048) {
        unsigned* rh = (unsigned*)hreg;
        for (int g = tid; g < NRB; g += NT) rh[g] = 0u;
        __syncthreads();
        int gmin = (bst - 1) << 6;
        for (int j = tid; j < count; j += NT) {
            unsigned u = (unsigned)(skey[j] >> 32);
            int rel = (int)(u >> RSH) - gmin;
            rel = rel < 0 ? 0 : (rel > NRB - 1 ? NRB - 1 : rel);
            atomicAdd(&rh[rel], 1u);
        }
        __syncthreads();
        int b2i = tid * 2;
        int d0 = rh[b2i], d1 = rh[b2i + 1];
        int t1 = d1, t0 = d1 + d0;
        int above = wave_suffix_above(t0, tid, wqi);
        int best = -1;
        if (t1 + above >= k) best = b2i + 1;
        else if (t0 + above >= k) best = b2i;
        if (best >= 0) atomicMax(&rb_s, best);
        __syncthreads();
        int rb = rb_s;
        ull* tmpc = hreg;   // rh dead (all reads happened pre-barrier)
        for (int j = tid; j < count; j += NT) {
            unsigned u = (unsigned)(skey[j] >> 32);
            int rel = (int)(u >> RSH) - gmin;
            rel = rel < 0 ? 0 : (rel > NRB - 1 ? NRB - 1 : rel);
            if (rel >= rb) {
                int pos = atomicAdd(&pcnt_s, 1);
                if (pos < PCAP) tmpc[pos] = skey[j];
            }
        }
        __syncthreads();
        int count2 = pcnt_s;
        if (count2 <= PCAP) {   // upward-closed in u => rank-preserving
            for (int j = tid; j < count2; j += NT) skey[j] = tmpc[j];
            count = count2;
        }
        __syncthreads();
    }

    // ---- Phase E: bitonic sort descending on (u desc, idx asc) ----
    int m = 1; while (m < count) m <<= 1;
    for (int j = count + tid; j < m; j += NT) skey[j] = 0ull;
    __syncthreads();
    for (int kk = 2; kk <= m; kk <<= 1) {
        for (int jj = kk >> 1; jj > 0; jj >>= 1) {
            for (int i2 = tid; i2 < m; i2 += NT) {
                int ixj = i2 ^ jj;
                if (ixj > i2) {
                    ull A = skey[i2], B = skey[ixj];
                    bool up = ((i2 & kk) != 0);
                    if ((A > B) == up) { skey[i2] = B; skey[ixj] = A; }
                }
            }
            __syncthreads();
        }
    }

    // ---- Phase F: exp, exact cumsum (shuffle scan), select, scatter ----
    for (int j = tid; j < CAP; j += NT)
        se[j] = (j < count) ? __expf(inv_mono((unsigned)(skey[j] >> 32))) : 0.0f;
    __syncthreads();
    int j0 = tid << 3;
    float ee[8], cc[8];
    float run = 0.0f;
#pragma unroll
    for (int q = 0; q < 8; ++q) { ee[q] = se[j0 + q]; run += ee[q]; cc[q] = run; }
    {
        int lane = tid & 63, wv = tid >> 6;
        float v = run;
#pragma unroll
        for (int off = 1; off < 64; off <<= 1) {
            float x = __shfl_up(v, off);
            if (lane >= off) v += x;
        }
        if (lane == 63) wqf[wv] = v;   // wave total
        __syncthreads();
        float wpre = 0.0f;
        for (int w = 0; w < wv; ++w) wpre += wqf[w];
        float pre = wpre + (v - run);

        float pS = topp_v[row] * Sp;
#pragma unroll
        for (int q = 0; q < 8; ++q) {
            int j = j0 + q;
            if (j < count) {
                float e = ee[q];
                float excl = __fsub_rn(pre + cc[q], e);
                if ((j < k) && (excl <= pS)) {
                    unsigned idx = ~(unsigned)(skey[j] & 0xffffffffull);
                    out[(size_t)row * V + idx] = __fdiv_rn(e, Sp);
                }
            }
        }
    }
}

extern "C" void kernel_launch(void* const* d_in, const int* in_sizes, int n_in,
                              void* d_out, int out_size, void* d_ws, size_t ws_size,
                              hipStream_t stream) {
    const float* logits = (const float*)d_in[0];
    const float* pres   = (const float*)d_in[1];
    const float* freq   = (const float*)d_in[2];
    const float* temps  = (const float*)d_in[3];
    const float* topps  = (const float*)d_in[4];
    const int*   tokens = (const int*)d_in[5];
    const int*   topks  = (const int*)d_in[6];
    int N = in_sizes[1];
    int V = in_sizes[0] / N;
    int H = in_sizes[5] / N;
    float* out = (float*)d_out;

    k_fused<<<N, NT, 0, stream>>>(logits, tokens, pres, freq, temps, topps,
                                  topks, V, H, out);
}